// Round 1
// baseline (270.963 us; speedup 1.0000x reference)
//
#include <hip/hip_runtime.h>

#define TILE 16
#define RR 8
#define ND 17          // 2r+1 displacements per axis
#define WIN 32         // tile + 2r
#define WSTRIDE 36     // window LDS row stride (16B-aligned, 2-way bank alias = free)
#define SSTRIDE 20     // src LDS row stride (16B-aligned, 2-way bank alias = free)
#define NTH 32
#define NTW 32
#define HH 512
#define WW 512
#define CC 3
#define BB 4
#define BLK 320        // 5 waves; 272 logical workers (17 dy-groups x 16 rows)

__launch_bounds__(BLK)
__global__ void tm_kernel(const float* __restrict__ src,
                          const float* __restrict__ dst,
                          const int* __restrict__ offset,
                          float* __restrict__ out) {
    __shared__ float Wl[CC * WIN * WSTRIDE];   // 3*32*36*4 = 13824 B
    __shared__ float Sl[CC * TILE * SSTRIDE];  // 3*16*20*4 =  3840 B
    __shared__ float costL[ND * ND];
    __shared__ int bestD;

    const int bid = blockIdx.x;
    const int b  = bid >> 10;
    const int th = (bid >> 5) & 31;
    const int tw = bid & 31;
    const int t  = threadIdx.x;

    const int ti = th * TILE;
    const int tj = tw * TILE;
    const int oy = offset[((b * 2 + 0) * NTH + th) * NTW + tw];
    const int ox = offset[((b * 2 + 1) * NTH + th) * NTW + tw];

    // ---- phase 1: stage zero-padded dst window + src tile into LDS ----
    const int base_y = ti + oy - RR;   // window row 0 in (unpadded) dst coords
    const int base_x = tj + ox - RR;
    for (int idx = t; idx < CC * WIN * WIN; idx += BLK) {
        int c   = idx >> 10;        // / (32*32)
        int rem = idx & 1023;
        int k   = rem >> 5;
        int l   = rem & 31;
        int y = base_y + k;
        int x = base_x + l;
        float v = 0.f;
        if ((unsigned)y < HH && (unsigned)x < WW)
            v = dst[((b * CC + c) * HH + y) * WW + x];
        Wl[c * (WIN * WSTRIDE) + k * WSTRIDE + l] = v;
    }
    for (int idx = t; idx < CC * TILE * TILE; idx += BLK) {
        int c   = idx >> 8;
        int rem = idx & 255;
        int i   = rem >> 4;
        int j   = rem & 15;
        Sl[c * (TILE * SSTRIDE) + i * SSTRIDE + j] =
            src[((b * CC + c) * HH + ti + i) * WW + tj + j];
    }
    __syncthreads();

    // ---- phase 2: register-sliding SAD rows ----
    // thread -> (dy, i); threads 272..319 recompute dy=16 (harmless, keeps
    // shuffle groups fully populated)
    int dy = t >> 4; if (dy > ND - 1) dy = ND - 1;
    const int i = t & 15;

    float acc[ND];
    #pragma unroll
    for (int d = 0; d < ND; ++d) acc[d] = 0.f;

    for (int c = 0; c < CC; ++c) {
        float S[TILE];
        const float* sp = &Sl[c * (TILE * SSTRIDE) + i * SSTRIDE];
        #pragma unroll
        for (int j = 0; j < TILE; ++j) S[j] = sp[j];
        float Wr[WIN];
        const float* wp = &Wl[c * (WIN * WSTRIDE) + (dy + i) * WSTRIDE];
        #pragma unroll
        for (int m = 0; m < WIN; ++m) Wr[m] = wp[m];
        #pragma unroll
        for (int dx = 0; dx < ND; ++dx) {
            float a = acc[dx];
            #pragma unroll
            for (int j = 0; j < TILE; ++j)
                a += fabsf(Wr[dx + j] - S[j]);
            acc[dx] = a;
        }
    }

    // reduce over i: 16-lane xor-shuffle tree within each dy group
    #pragma unroll
    for (int m = 1; m <= 8; m <<= 1) {
        #pragma unroll
        for (int d = 0; d < ND; ++d)
            acc[d] += __shfl_xor(acc[d], m);
    }
    if ((t & 15) == 0 && (t >> 4) <= ND - 1) {
        #pragma unroll
        for (int d = 0; d < ND; ++d)
            costL[dy * ND + d] = acc[d];
    }
    __syncthreads();

    // ---- argmin over 289 costs (wave 0), tie -> smallest d ----
    if (t < 64) {
        float bc = 3.4e38f;
        int bi = 0;
        for (int e = t; e < ND * ND; e += 64) {  // increasing e: strict < keeps smallest
            float cv = costL[e];
            if (cv < bc) { bc = cv; bi = e; }
        }
        #pragma unroll
        for (int m = 1; m <= 32; m <<= 1) {
            float oc = __shfl_xor(bc, m);
            int   oi = __shfl_xor(bi, m);
            if (oc < bc || (oc == bc && oi < bi)) { bc = oc; bi = oi; }
        }
        if (t == 0) bestD = bi;
    }
    __syncthreads();

    const int bd  = bestD;
    const int bdy = bd / ND;
    const int bdx = bd - bdy * ND;

    // ---- outputs: new_off (as float32) then aligned ----
    if (t == 0) {
        out[((b * 2 + 0) * NTH + th) * NTW + tw] = (float)(oy + bdy - RR);
        out[((b * 2 + 1) * NTH + th) * NTW + tw] = (float)(ox + bdx - RR);
    }
    float* aligned = out + BB * 2 * NTH * NTW;  // 8192 floats of new_off first
    if (t < 256) {
        const int ii = t >> 4, jj = t & 15;
        #pragma unroll
        for (int c = 0; c < CC; ++c) {
            aligned[((b * CC + c) * HH + ti + ii) * WW + tj + jj] =
                Wl[c * (WIN * WSTRIDE) + (bdy + ii) * WSTRIDE + bdx + jj];
        }
    }
}

extern "C" void kernel_launch(void* const* d_in, const int* in_sizes, int n_in,
                              void* d_out, int out_size, void* d_ws, size_t ws_size,
                              hipStream_t stream) {
    const float* src    = (const float*)d_in[0];
    const float* dst    = (const float*)d_in[1];
    const int*   offset = (const int*)d_in[2];
    float*       out    = (float*)d_out;
    dim3 grid(BB * NTH * NTW);   // 4096 tiles, one block each
    tm_kernel<<<grid, BLK, 0, stream>>>(src, dst, offset, out);
}

// Round 2
// 165.040 us; speedup vs baseline: 1.6418x; 1.6418x over previous
//
#include <hip/hip_runtime.h>

#define TILE 16
#define RR 8
#define ND 17          // 2r+1 displacements per axis
#define PW 544         // padded dst width/height (512 + 2*16)
#define PPAD 16
#define HH 512
#define WW 512
#define CC 3
#define BB 4
#define NTH 32
#define NTW 32
#define CSTRIDE 20     // cost row stride in floats (16B-aligned rows)

// ---------------- kernel 1: zero-padded dst copy into workspace ------------
__global__ __launch_bounds__(256) void pad_kernel(const float* __restrict__ dst,
                                                  float* __restrict__ P) {
    const int groups_per_row = PW / 4;               // 136
    const int groups_per_img = PW * groups_per_row;  // 73984
    int idx = blockIdx.x * 256 + threadIdx.x;
    if (idx >= BB * CC * groups_per_img) return;
    int bc  = idx / groups_per_img;
    int rem = idx - bc * groups_per_img;
    int y   = rem / groups_per_row;
    int x   = (rem - y * groups_per_row) * 4;
    float4 v = make_float4(0.f, 0.f, 0.f, 0.f);
    if (y >= PPAD && y < PPAD + HH && x >= PPAD && x < PPAD + WW) {
        v = *(const float4*)(dst + ((size_t)bc * HH + (y - PPAD)) * WW + (x - PPAD));
    }
    *(float4*)(P + ((size_t)bc * PW + y) * PW + x) = v;
}

// DPP add helper: x + dpp_perm(x). ctrl must be a compile-time constant.
template <int CTRL>
__device__ __forceinline__ float dpp_add(float x) {
    union { float f; int i; } u, v;
    u.f = x;
    v.i = __builtin_amdgcn_update_dpp(0, u.i, CTRL, 0xF, 0xF, true);
    return x + v.f;
}

// ---------------- kernel 2: one wave per (tile, dy), no LDS, no barriers ---
__global__ __launch_bounds__(64, 4) void sad_kernel(const float* __restrict__ src,
                                                    const float* __restrict__ P,
                                                    const int* __restrict__ offset,
                                                    float* __restrict__ cost) {
    // XCD-banding swizzle: assuming round-robin blockIdx%8 -> XCD, give each
    // XCD a contiguous range of 512 tiles (its own image band) with the 17
    // dy-blocks of a tile consecutive in time for L1/L2 reuse.
    const int L  = blockIdx.x;          // 0 .. 4096*17-1
    const int r  = L & 7;
    const int g  = L >> 3;              // 0 .. 8703
    const int tq = g / ND;              // 0 .. 511
    const int dy = g - tq * ND;
    const int tile = r * 512 + tq;
    const int b  = tile >> 10;
    const int th = (tile >> 5) & 31;
    const int tw = tile & 31;
    const int ti = th * TILE, tj = tw * TILE;
    const int oy = offset[(b * 2 + 0) * (NTH * NTW) + th * NTW + tw];
    const int ox = offset[(b * 2 + 1) * (NTH * NTW) + th * NTW + tw];

    const int lane = threadIdx.x;
    const int i  = lane >> 2;          // source row 0..15
    const int jg = lane & 3;           // 4-wide j chunk
    const int s  = ox & 3;             // wave-uniform alignment shift
    const int rowP = ti + oy + 8 + dy + i;            // in [8, 543]
    const int colA = tj + (ox & ~3) + 8 + jg * 4;     // 16B-aligned col base

    float acc[ND];
    #pragma unroll
    for (int d = 0; d < ND; ++d) acc[d] = 0.f;

    for (int c = 0; c < CC; ++c) {
        const float* wrow = P + ((size_t)((b * CC + c) * PW + rowP)) * PW + colA;
        float raw[24];
        #pragma unroll
        for (int k = 0; k < 6; ++k) {
            float4 t4 = *(const float4*)(wrow + 4 * k);
            raw[4 * k + 0] = t4.x; raw[4 * k + 1] = t4.y;
            raw[4 * k + 2] = t4.z; raw[4 * k + 3] = t4.w;
        }
        float w[20];
        if (s == 0) {            // scalar branch: s is wave-uniform
            #pragma unroll
            for (int m = 0; m < 20; ++m) w[m] = raw[m];
        } else if (s == 1) {
            #pragma unroll
            for (int m = 0; m < 20; ++m) w[m] = raw[m + 1];
        } else if (s == 2) {
            #pragma unroll
            for (int m = 0; m < 20; ++m) w[m] = raw[m + 2];
        } else {
            #pragma unroll
            for (int m = 0; m < 20; ++m) w[m] = raw[m + 3];
        }
        float4 sv = *(const float4*)(src + ((size_t)((b * CC + c) * HH + ti + i)) * WW
                                     + tj + 4 * jg);
        float ss0 = sv.x, ss1 = sv.y, ss2 = sv.z, ss3 = sv.w;
        #pragma unroll
        for (int dx = 0; dx < ND; ++dx) {
            float a = acc[dx];
            a += fabsf(w[dx + 0] - ss0);
            a += fabsf(w[dx + 1] - ss1);
            a += fabsf(w[dx + 2] - ss2);
            a += fabsf(w[dx + 3] - ss3);
            acc[dx] = a;
        }
    }

    // 64-lane sum: 4 DPP rounds (VALU pipe) + 2 cross-row shuffles
    #pragma unroll
    for (int d = 0; d < ND; ++d) {
        float x = acc[d];
        x = dpp_add<0xB1>(x);    // quad_perm [1,0,3,2]  (xor 1)
        x = dpp_add<0x4E>(x);    // quad_perm [2,3,0,1]  (xor 2)
        x = dpp_add<0x141>(x);   // row_half_mirror      (pairs 8-halves)
        x = dpp_add<0x140>(x);   // row_mirror           (pairs 16-halves)
        x += __shfl_xor(x, 16);
        x += __shfl_xor(x, 32);
        acc[d] = x;
    }
    if (lane == 0) {
        float* cp = cost + (size_t)(tile * ND + dy) * CSTRIDE;
        *(float4*)(cp + 0)  = make_float4(acc[0],  acc[1],  acc[2],  acc[3]);
        *(float4*)(cp + 4)  = make_float4(acc[4],  acc[5],  acc[6],  acc[7]);
        *(float4*)(cp + 8)  = make_float4(acc[8],  acc[9],  acc[10], acc[11]);
        *(float4*)(cp + 12) = make_float4(acc[12], acc[13], acc[14], acc[15]);
        cp[16] = acc[16];
    }
}

// ---------------- kernel 3: per-tile argmin + aligned gather ---------------
__global__ __launch_bounds__(64) void argmin_gather_kernel(const float* __restrict__ P,
                                                           const int* __restrict__ offset,
                                                           const float* __restrict__ cost,
                                                           float* __restrict__ out) {
    const int tile = blockIdx.x;
    const int b  = tile >> 10;
    const int th = (tile >> 5) & 31;
    const int tw = tile & 31;
    const int ti = th * TILE, tj = tw * TILE;
    const int t  = threadIdx.x;
    const int oy = offset[(b * 2 + 0) * (NTH * NTW) + th * NTW + tw];
    const int ox = offset[(b * 2 + 1) * (NTH * NTW) + th * NTW + tw];

    float bc = 3.4e38f;
    int   bi = 0;
    for (int e = t; e < ND * ND; e += 64) {   // e increasing: strict < keeps smallest
        int edy = e / ND;
        int edx = e - edy * ND;
        float cv = cost[(size_t)(tile * ND + edy) * CSTRIDE + edx];
        if (cv < bc) { bc = cv; bi = e; }
    }
    #pragma unroll
    for (int m = 1; m <= 32; m <<= 1) {
        float oc = __shfl_xor(bc, m);
        int   oi = __shfl_xor(bi, m);
        if (oc < bc || (oc == bc && oi < bi)) { bc = oc; bi = oi; }
    }
    const int bdy = bi / ND;
    const int bdx = bi - bdy * ND;

    if (t == 0) {
        out[(b * 2 + 0) * (NTH * NTW) + th * NTW + tw] = (float)(oy + bdy - RR);
        out[(b * 2 + 1) * (NTH * NTW) + th * NTW + tw] = (float)(ox + bdx - RR);
    }
    float* aligned = out + BB * 2 * NTH * NTW;
    const int prow0 = ti + oy + bdy + 8;   // P row of aligned tile's row 0
    const int pcol0 = tj + ox + bdx + 8;
    #pragma unroll
    for (int k = 0; k < 12; ++k) {
        int idx = t + 64 * k;              // 0..767 -> (c, ii, jj)
        int c  = idx >> 8;
        int ii = (idx >> 4) & 15;
        int jj = idx & 15;
        float v = P[((size_t)((b * CC + c) * PW + prow0 + ii)) * PW + pcol0 + jj];
        aligned[((size_t)((b * CC + c) * HH + ti + ii)) * WW + tj + jj] = v;
    }
}

extern "C" void kernel_launch(void* const* d_in, const int* in_sizes, int n_in,
                              void* d_out, int out_size, void* d_ws, size_t ws_size,
                              hipStream_t stream) {
    const float* src    = (const float*)d_in[0];
    const float* dst    = (const float*)d_in[1];
    const int*   offset = (const int*)d_in[2];
    float*       out    = (float*)d_out;

    float* P    = (float*)d_ws;                       // 12*544*544 floats = 14.2 MB
    float* cost = P + (size_t)BB * CC * PW * PW;      // 4096*17*20 floats = 5.6 MB

    const int pad_groups = BB * CC * PW * (PW / 4);   // 887808
    pad_kernel<<<dim3((pad_groups + 255) / 256), 256, 0, stream>>>(dst, P);
    sad_kernel<<<dim3(BB * NTH * NTW * ND), 64, 0, stream>>>(src, P, offset, cost);
    argmin_gather_kernel<<<dim3(BB * NTH * NTW), 64, 0, stream>>>(P, offset, cost, out);
}